// Round 12
// baseline (532.813 us; speedup 1.0000x reference)
//
#include <hip/hip_runtime.h>
#include <hip/hip_bf16.h>
#include <stdint.h>

// SelfAttention: out = softmax((x Wq^T)(x Wk^T)^T / sqrt(D)) (x Wv^T)
// SEQ=8192, D=1024, fp32 in/out. All GEMMs bf16 MFMA (absmax ~2.4e-4).
// R21 = R20 composition + PV split-K 2->4 with atomic-add epilogue.
// R20 accounting: S 194 | PV ~166 | QKV ~63 | transpose 10 | add 15 | conv 9.
// PV was grid-limited: 512 blocks = 2/CU vs static cap 3 (48KB LDS).
// Split-4 -> 1024 blocks -> 3/CU. MODE 3 epilogue: atomicAdd(out, acc/l)
// into pre-zeroed out (device-scope fp32 atomics, m20) -> no partial
// buffers, no add_f32 pass. Total operand traffic is split-invariant
// (S 128MB and v^T 16MB are L3-resident).
// Flash fusion ruled out by arithmetic: D=1024 -> 64-row Q-tile needs
// 256KB fp32 output accumulator per block (>=128 VGPR/thread) — the
// materialized-S decomposition is structurally right for this shape.
//  - S-GEMM (MODE1): gemm32 (BK=32, 16KB LDS, phase-bijective rotation,
//    0 conflicts, XCD chunk).
//  - QKV (MODE0): gemm_hn 128x256 BK=64. PV (MODE3): gemm_hn split-4.
// Keeps: compact q/k/v de-interleave, fused softmax epilogues, GROUP_M=8.
//
// Workspace (~230 MB): x_bf16 16 | Wcat 6 | q 16 | k 16 | v 16 | S 128
//                      | (pvp slot unused) | lsum 32KB

#define SEQ 8192
#define DMODEL 1024
#define LOG2E 1.44269504088896340736f
#define GROUP_M 8

typedef __bf16 bf16_t;
typedef __bf16 bf16x8 __attribute__((ext_vector_type(8)));
typedef float f32x4 __attribute__((ext_vector_type(4)));

// ---------------- fp32 -> bf16 convert ----------------
__global__ __launch_bounds__(256)
void convert_f32_bf16(const float* __restrict__ in, bf16_t* __restrict__ out, long n) {
    long i = ((long)blockIdx.x * 256 + threadIdx.x) * 4;
    if (i + 3 < n) {
        const float4 v = *(const float4*)(in + i);
        union { ushort4 u; bf16_t b[4]; } p;
        p.b[0] = (bf16_t)v.x; p.b[1] = (bf16_t)v.y;
        p.b[2] = (bf16_t)v.z; p.b[3] = (bf16_t)v.w;
        *(ushort4*)(out + i) = p.u;
    }
}

// ---------------- zero fp32 buffer (float4) ----------------
__global__ __launch_bounds__(256)
void zero4_f32(float* __restrict__ p, long n) {
    long i = ((long)blockIdx.x * 256 + threadIdx.x) * 4;
    if (i + 3 < n) {
        float4 z; z.x = 0.f; z.y = 0.f; z.z = 0.f; z.w = 0.f;
        *(float4*)(p + i) = z;
    }
}

// ---------------- zero fp32 buffer (scalar, small) ----------------
__global__ __launch_bounds__(256)
void zero_f32(float* __restrict__ p, int n) {
    int i = blockIdx.x * 256 + threadIdx.x;
    if (i < n) p[i] = 0.0f;
}

// ======================================================================
// gemm_hn: 128x256 tile, BK=64, 512 threads (8 waves as 2x4), per-wave
// 64x64 via 4x4 grid of mfma_f32_16x16x32_bf16. Single-buffered loop:
// stage(A:2+B:4 gload_lds/thread) -> sync -> 2 x {8 frag ds_reads +
// 16 MFMA} -> sync. Row-rotation swizzle (128B rows) -> 0 conflicts.
// XCD chunk + GROUP_M. MODE 0: C = alpha*acc.
// MODE 3: atomicAdd(C, acc / lsum[row])  (PV split-K accumulation).
// ======================================================================
template <typename OutT, int MODE>
__global__ __launch_bounds__(512, 2)
void gemm_hn(const bf16_t* __restrict__ A, const bf16_t* __restrict__ B,
             OutT* __restrict__ C0, OutT* __restrict__ C1,
             float* __restrict__ lsum,
             int M, int N, int Kps, int lda, int ldb, int ldc,
             long plane, int cshift, float alpha)
{
    __shared__ bf16_t As[128 * 64];   // 16KB
    __shared__ bf16_t Bs[256 * 64];   // 32KB

    const int tid  = threadIdx.x;
    const int wave = tid >> 6;
    const int lane = tid & 63;

    const int nbm = M >> 7, nbn = N >> 8;
    const int tiles = nbm * nbn;
    int bid = blockIdx.x;
    const int sid = bid / tiles;        // split-K id
    bid -= sid * tiles;
    const long kbase = (long)sid * Kps;
    OutT* __restrict__ C = C0;          // MODE3: all splits atomically add

    // XCD-chunked swizzle (bijective: tiles % 8 == 0 for our launches).
    const int cpx = tiles >> 3;
    bid = (bid & 7) * cpx + (bid >> 3);

    // grouped swizzle (GROUP_M row-tiles, col-major inside)
    const int per_group = GROUP_M * nbn;
    const int gid   = bid / per_group;
    const int rem   = bid - gid * per_group;
    const int first = gid * GROUP_M;
    const int gsz   = min(nbm - first, GROUP_M);
    const int bm    = first + rem % gsz;
    const int bn    = rem / gsz;
    const long row0 = (long)bm * 128;
    const long col0 = (long)bn * 256;

    const int wm = (wave >> 2) * 64;   // 2 row-waves
    const int wn = (wave & 3) * 64;    // 4 col-waves
    const int lr = lane & 15;          // fragment non-K index
    const int lq = lane >> 4;          // quad 0..3 -> k-chunk / row group

    // staging: rows rt=tid>>3 per 64-row block i; phys slot p=tid&7 holds
    // global chunk (p+r)&7 (rotation within the 128B row); r&7 == rt&7.
    const int rt = tid >> 3;
    const int sl = ((tid & 7) + rt) & 7;
    const bf16_t* pa = A + (row0 + rt) * (long)lda + kbase + sl * 8;
    const bf16_t* pb = B + (col0 + rt) * (long)ldb + kbase + sl * 8;

    // LDS read slot: chunk g at row r lives at p=(g-r)&7; r&7 == lr&7.
    const int p0  = (lq - lr) & 7;          // t=0 chunk = lq
    const int p1  = p0 ^ 4;                 // t=1 chunk = 4+lq
    const int oA0 = (wm + lr) * 64 + p0 * 8;
    const int oA1 = (wm + lr) * 64 + p1 * 8;
    const int oB0 = (wn + lr) * 64 + p0 * 8;
    const int oB1 = (wn + lr) * 64 + p1 * 8;

    f32x4 acc[4][4] = {};

    for (int k0 = 0; k0 < Kps; k0 += 64) {
        // Stage A (128x64: 2 chunks/thread) + B (256x64: 4 chunks/thread).
        #pragma unroll
        for (int i = 0; i < 2; ++i) {
            const bf16_t* ga = pa + k0 + (long)i * 64 * lda;
            __builtin_amdgcn_global_load_lds(
                (const __attribute__((address_space(1))) uint32_t*)ga,
                (__attribute__((address_space(3))) uint32_t*)(As + i * 4096 + tid * 8),
                16, 0, 0);
        }
        #pragma unroll
        for (int i = 0; i < 4; ++i) {
            const bf16_t* gb = pb + k0 + (long)i * 64 * ldb;
            __builtin_amdgcn_global_load_lds(
                (const __attribute__((address_space(1))) uint32_t*)gb,
                (__attribute__((address_space(3))) uint32_t*)(Bs + i * 4096 + tid * 8),
                16, 0, 0);
        }
        __syncthreads();

        #pragma unroll
        for (int t = 0; t < 2; ++t) {   // two K=32 MFMA steps per staged tile
            bf16x8 af[4], bfr[4];
            const int oA = t ? oA1 : oA0;
            const int oB = t ? oB1 : oB0;
            #pragma unroll
            for (int mi = 0; mi < 4; ++mi)
                af[mi] = *(const bf16x8*)(As + oA + mi * 1024);
            #pragma unroll
            for (int ni = 0; ni < 4; ++ni)
                bfr[ni] = *(const bf16x8*)(Bs + oB + ni * 1024);
            #pragma unroll
            for (int mi = 0; mi < 4; ++mi)
                #pragma unroll
                for (int ni = 0; ni < 4; ++ni)
                    acc[mi][ni] = __builtin_amdgcn_mfma_f32_16x16x32_bf16(
                        af[mi], bfr[ni], acc[mi][ni], 0, 0, 0);
        }
        __syncthreads();
    }

    // Epilogue: C/D layout col=lane&15, row=(lane>>4)*4+reg  [m89/m91]
    OutT* __restrict__ Cb = C + (col0 >> cshift) * plane;
    const int ccol0 = (int)(col0 & (((long)1 << cshift) - 1));

    if (MODE == 3) {
        // PV split-K: out += acc / lsum[row]  (out pre-zeroed; device-scope
        // fp32 atomics are XCD-safe, m20).
        #pragma unroll
        for (int mi = 0; mi < 4; ++mi)
            #pragma unroll
            for (int rg = 0; rg < 4; ++rg) {
                const long r = row0 + wm + mi * 16 + lq * 4 + rg;
                const float inv = 1.0f / lsum[r];
                #pragma unroll
                for (int ni = 0; ni < 4; ++ni) {
                    const int c = ccol0 + wn + ni * 16 + lr;
                    atomicAdd((float*)&Cb[r * (long)ldc + c],
                              acc[mi][ni][rg] * inv);
                }
            }
    } else {
        #pragma unroll
        for (int mi = 0; mi < 4; ++mi)
            #pragma unroll
            for (int ni = 0; ni < 4; ++ni)
                #pragma unroll
                for (int rg = 0; rg < 4; ++rg) {
                    const long r = row0 + wm + mi * 16 + lq * 4 + rg;
                    const int  c = ccol0 + wn + ni * 16 + lr;
                    Cb[r * (long)ldc + c] = (OutT)(alpha * acc[mi][ni][rg]);
                }
    }
}

// ======================================================================
// gemm32: 128x128 tile, BK=32, 256 threads (4 waves 2x2), wave 64x64 via
// 4x4 grid of mfma_f32_16x16x32_bf16. 16KB LDS -> high occupancy.
// (r>>1)-rotation swizzle: phase-bijective -> 0 bank conflicts (R18).
// XCD chunking + GROUP_M. Used for the S-GEMM (MODE1).
// ======================================================================
template <typename OutT, int MODE>
__global__ __launch_bounds__(256, 3)
void gemm32(const bf16_t* __restrict__ A, const bf16_t* __restrict__ B,
            OutT* __restrict__ C0, OutT* __restrict__ C1,
            float* __restrict__ lsum,
            int M, int N, int Kps, int lda, int ldb, int ldc,
            long plane, int cshift, float alpha)
{
    __shared__ bf16_t As[128 * 32];   // 8KB
    __shared__ bf16_t Bs[128 * 32];   // 8KB

    const int tid  = threadIdx.x;
    const int wave = tid >> 6;
    const int lane = tid & 63;

    const int nbm = M >> 7, nbn = N >> 7;
    const int tiles = nbm * nbn;
    int bid = blockIdx.x;
    const int sid = bid / tiles;
    bid -= sid * tiles;
    const long kbase = (long)sid * Kps;
    OutT* __restrict__ C = sid ? C1 : C0;

    const int cpx = tiles >> 3;
    bid = (bid & 7) * cpx + (bid >> 3);

    const int per_group = GROUP_M * nbn;
    const int gid   = bid / per_group;
    const int rem   = bid - gid * per_group;
    const int first = gid * GROUP_M;
    const int gsz   = min(nbm - first, GROUP_M);
    const int bm    = first + rem % gsz;
    const int bn    = rem / gsz;
    const long row0 = (long)bm * 128;
    const long col0 = (long)bn * 128;

    const int wm = (wave >> 1) * 64;
    const int wn = (wave & 1) * 64;
    const int lr = lane & 15;
    const int lq = lane >> 4;

    // staging: chunk c=i*256+tid; row r=c>>2, phys slot p=c&3 holds global
    // chunk l=(p+(r>>1))&3; thread-constant l=((tid&3)+((tid>>3)&3))&3.
    const int rt = tid >> 2;
    const int sl = ((tid & 3) + ((tid >> 3) & 3)) & 3;
    const bf16_t* pa = A + (row0 + rt) * (long)lda + kbase + sl * 8;
    const bf16_t* pb = B + (col0 + rt) * (long)ldb + kbase + sl * 8;

    // read slot: p0=(lq-((r>>1)&3))&3; (r>>1)&3 == (lr>>1)&3.
    const int p0  = (lq - ((lr >> 1) & 3)) & 3;
    const int oA  = (wm + lr) * 32 + p0 * 8;
    const int oB  = (wn + lr) * 32 + p0 * 8;

    f32x4 acc[4][4] = {};

    for (int k0 = 0; k0 < Kps; k0 += 32) {
        #pragma unroll
        for (int i = 0; i < 2; ++i) {
            const bf16_t* ga = pa + k0 + (long)i * 64 * lda;
            const bf16_t* gb = pb + k0 + (long)i * 64 * ldb;
            __builtin_amdgcn_global_load_lds(
                (const __attribute__((address_space(1))) uint32_t*)ga,
                (__attribute__((address_space(3))) uint32_t*)(As + (long)(i * 256 + tid) * 8),
                16, 0, 0);
            __builtin_amdgcn_global_load_lds(
                (const __attribute__((address_space(1))) uint32_t*)gb,
                (__attribute__((address_space(3))) uint32_t*)(Bs + (long)(i * 256 + tid) * 8),
                16, 0, 0);
        }
        __syncthreads();

        bf16x8 af[4], bfr[4];
        #pragma unroll
        for (int mi = 0; mi < 4; ++mi)
            af[mi] = *(const bf16x8*)(As + oA + mi * 512);
        #pragma unroll
        for (int ni = 0; ni < 4; ++ni)
            bfr[ni] = *(const bf16x8*)(Bs + oB + ni * 512);
        #pragma unroll
        for (int mi = 0; mi < 4; ++mi)
            #pragma unroll
            for (int ni = 0; ni < 4; ++ni)
                acc[mi][ni] = __builtin_amdgcn_mfma_f32_16x16x32_bf16(
                    af[mi], bfr[ni], acc[mi][ni], 0, 0, 0);
        __syncthreads();
    }

    OutT* __restrict__ Cb = C + (col0 >> cshift) * plane;
    const int ccol0 = (int)(col0 & (((long)1 << cshift) - 1));

    if (MODE == 1) {
        #pragma unroll
        for (int mi = 0; mi < 4; ++mi)
            #pragma unroll
            for (int rg = 0; rg < 4; ++rg) {
                const long r = row0 + wm + mi * 16 + lq * 4 + rg;
                float part = 0.f;
                #pragma unroll
                for (int ni = 0; ni < 4; ++ni) {
                    const int c = ccol0 + wn + ni * 16 + lr;
                    const float e = exp2f(alpha * acc[mi][ni][rg]);
                    part += e;
                    Cb[r * (long)ldc + c] = (OutT)e;
                }
                part += __shfl_xor(part, 1);
                part += __shfl_xor(part, 2);
                part += __shfl_xor(part, 4);
                part += __shfl_xor(part, 8);
                if (lr == 0) atomicAdd(&lsum[r], part);
            }
    } else {
        #pragma unroll
        for (int mi = 0; mi < 4; ++mi)
            #pragma unroll
            for (int ni = 0; ni < 4; ++ni)
                #pragma unroll
                for (int rg = 0; rg < 4; ++rg) {
                    const long r = row0 + wm + mi * 16 + lq * 4 + rg;
                    const int  c = ccol0 + wn + ni * 16 + lr;
                    Cb[r * (long)ldc + c] = (OutT)(alpha * acc[mi][ni][rg]);
                }
    }
}

// ---------------- bf16 transpose (strided in), v -> v^T ----------------
__global__ __launch_bounds__(256)
void transpose_bf16(const bf16_t* __restrict__ in, bf16_t* __restrict__ out,
                    int R, int ldin, int ldout)
{
    __shared__ bf16_t tile[32][33];
    const int tx = threadIdx.x & 31;
    const int ty = threadIdx.x >> 5;   // 0..7
    const int c0 = blockIdx.x * 32;
    const int r0 = blockIdx.y * 32;
    #pragma unroll
    for (int j = 0; j < 32; j += 8)
        tile[ty + j][tx] = in[(long)(r0 + ty + j) * ldin + c0 + tx];
    __syncthreads();
    #pragma unroll
    for (int j = 0; j < 32; j += 8)
        out[(long)(c0 + ty + j) * ldout + r0 + tx] = tile[tx][ty + j];
}

extern "C" void kernel_launch(void* const* d_in, const int* in_sizes, int n_in,
                              void* d_out, int out_size, void* d_ws, size_t ws_size,
                              hipStream_t stream)
{
    const float* x  = (const float*)d_in[0];
    const float* Wq = (const float*)d_in[1];
    const float* Wk = (const float*)d_in[2];
    const float* Wv = (const float*)d_in[3];
    float* out = (float*)d_out;

    char* ws = (char*)d_ws;
    const long XN = (long)SEQ * DMODEL;     // 8,388,608
    const long WN = (long)DMODEL * DMODEL;  // 1,048,576
    const long SN = (long)SEQ * SEQ;        // 67,108,864

    bf16_t* xb   = (bf16_t*)ws;                              // 16MB
    bf16_t* wcat = (bf16_t*)(ws + XN * 2);                   // 6MB [3072,1024]
    bf16_t* qb   = (bf16_t*)(ws + XN * 2 + WN * 6);          // 16MB compact
    bf16_t* kb   = qb + XN;                                  // 16MB compact
    bf16_t* vb   = qb + 2 * XN;                              // 16MB compact
    bf16_t* Sb   = (bf16_t*)(ws + XN * 2 + WN * 6 + XN * 6); // 128MB
    float*  lsum;
    bf16_t* vtb  = xb;  // v^T overlays x_bf16 (x dead after QKV GEMM)

    const size_t base_need = (size_t)(XN * 2 + WN * 6 + XN * 6 + SN * 2);
    // lsum: keep at the R20 (use_split) address when ws allows, else fallback.
    if (ws_size >= base_need + XN * 4 + SEQ * 4)
        lsum = (float*)(ws + base_need + XN * 4);
    else
        lsum = (float*)(ws + base_need);

    convert_f32_bf16<<<(int)(XN / 4 / 256), 256, 0, stream>>>(x,  xb, XN);
    convert_f32_bf16<<<(int)(WN / 4 / 256), 256, 0, stream>>>(Wq, wcat,          WN);
    convert_f32_bf16<<<(int)(WN / 4 / 256), 256, 0, stream>>>(Wk, wcat + WN,     WN);
    convert_f32_bf16<<<(int)(WN / 4 / 256), 256, 0, stream>>>(Wv, wcat + 2 * WN, WN);
    zero_f32<<<SEQ / 256, 256, 0, stream>>>(lsum, SEQ);

    dim3 blk256(256);
    dim3 blk512(512);
    // qkv = x @ Wcat^T, de-interleaved into compact q|k|v (plane=XN, cshift=10)
    gemm_hn<bf16_t, 0><<<(SEQ / 128) * (3 * DMODEL / 256), blk512, 0, stream>>>(
        xb, wcat, qb, qb, nullptr, SEQ, 3 * DMODEL, DMODEL,
        DMODEL, DMODEL, DMODEL, XN, 10, 1.0f);

    // v^T for the PV GEMM (writes over dead x_bf16)
    transpose_bf16<<<dim3(DMODEL / 32, SEQ / 32), blk256, 0, stream>>>(
        vb, vtb, SEQ, DMODEL, SEQ);

    // P' = exp2((q@k^T) * scale * log2e), bf16; row sums -> lsum (atomic)
    gemm32<bf16_t, 1><<<(SEQ / 128) * (SEQ / 128), blk256, 0, stream>>>(
        qb, kb, Sb, Sb, lsum, SEQ, SEQ, DMODEL,
        DMODEL, DMODEL, SEQ, 0, 30, 0.03125f * LOG2E);

    // out = (P' @ v) / l : split-K=4, atomicAdd into pre-zeroed out.
    zero4_f32<<<(int)(XN / 4 / 256), 256, 0, stream>>>(out, XN);
    gemm_hn<float, 3><<<4 * (SEQ / 128) * (DMODEL / 256), blk512, 0, stream>>>(
        Sb, vtb, out, out, lsum, SEQ, DMODEL, SEQ / 4,
        SEQ, SEQ, DMODEL, 0, 30, 1.0f);
}

// Round 13
// 458.928 us; speedup vs baseline: 1.1610x; 1.1610x over previous
//
#include <hip/hip_runtime.h>
#include <hip/hip_bf16.h>
#include <stdint.h>

// SelfAttention: out = softmax((x Wq^T)(x Wk^T)^T / sqrt(D)) (x Wv^T)
// SEQ=8192, D=1024, fp32 in/out. All GEMMs bf16 MFMA (absmax ~2.4e-4).
// R22 = R20 (457.3us, session best) + double-buffered gemm32 (S-GEMM).
// R21 (PV split-4 atomics) regressed: 128MB atomic RMW traffic, PV 166->192.
// gemm32 analysis (corrected per-SIMD MFMA cost ~19.4cyc/instr): MFMA floor
// 66us vs 190 measured; iter latency ~2900cyc (L2 drain exposed every iter:
// stage issued AFTER barrier, waited immediately) vs 890cyc issue rate at
// ~3.4 resident blocks. Fix: one-tile-ahead prefetch (T3-minimum 2-phase):
//   prologue STG(0); per iter: vmcnt(0) [t's loads, issued 1 iter ago];
//   s_barrier; STG(t+1 -> buf^1); ds_read buf; 16 MFMA.
// One barrier/iter (was 2); stage latency hidden under ~500cyc of compute.
// Hazard: buf's ds_reads complete before each wave's barrier -> next-iter
// DMA overwrite safe. LDS 16->32KB (cap 5/CU >= current 3.4).
//  - S-GEMM (MODE1): gemm32 dbuf (BK=32, phase-bijective rotation, XCD).
//  - QKV (MODE0) & PV (MODE2): gemm_hn 128x256 BK=64 (unchanged from R20).
// Keeps: compact q/k/v de-interleave, fused softmax epilogues, split-K=2 PV
// with pvp+add, GROUP_M=8 grouping.
//
// Workspace (~230 MB): x_bf16 16 | Wcat 6 | q 16 | k 16 | v 16 | S 128 | pv 32
//                      | lsum 32KB

#define SEQ 8192
#define DMODEL 1024
#define LOG2E 1.44269504088896340736f
#define GROUP_M 8

typedef __bf16 bf16_t;
typedef __bf16 bf16x8 __attribute__((ext_vector_type(8)));
typedef float f32x4 __attribute__((ext_vector_type(4)));

// ---------------- fp32 -> bf16 convert ----------------
__global__ __launch_bounds__(256)
void convert_f32_bf16(const float* __restrict__ in, bf16_t* __restrict__ out, long n) {
    long i = ((long)blockIdx.x * 256 + threadIdx.x) * 4;
    if (i + 3 < n) {
        const float4 v = *(const float4*)(in + i);
        union { ushort4 u; bf16_t b[4]; } p;
        p.b[0] = (bf16_t)v.x; p.b[1] = (bf16_t)v.y;
        p.b[2] = (bf16_t)v.z; p.b[3] = (bf16_t)v.w;
        *(ushort4*)(out + i) = p.u;
    }
}

// ---------------- fp32 add: out += part ----------------
__global__ __launch_bounds__(256)
void add_f32(float* __restrict__ out, const float* __restrict__ part, long n) {
    long i = ((long)blockIdx.x * 256 + threadIdx.x) * 4;
    if (i + 3 < n) {
        float4 a = *(const float4*)(out + i);
        const float4 b = *(const float4*)(part + i);
        a.x += b.x; a.y += b.y; a.z += b.z; a.w += b.w;
        *(float4*)(out + i) = a;
    }
}

// ---------------- zero fp32 buffer ----------------
__global__ __launch_bounds__(256)
void zero_f32(float* __restrict__ p, int n) {
    int i = blockIdx.x * 256 + threadIdx.x;
    if (i < n) p[i] = 0.0f;
}

// ======================================================================
// gemm_hn: 128x256 tile, BK=64, 512 threads (8 waves as 2x4), per-wave
// 64x64 via 4x4 grid of mfma_f32_16x16x32_bf16. Single-buffered loop:
// stage(A:2+B:4 gload_lds/thread) -> sync -> 2 x {8 frag ds_reads +
// 16 MFMA} -> sync. Row-rotation swizzle (128B rows) -> 0 conflicts.
// XCD chunk + GROUP_M. MODE 0: C = alpha*acc. MODE 2: C = acc/lsum[row].
// ======================================================================
template <typename OutT, int MODE>
__global__ __launch_bounds__(512, 2)
void gemm_hn(const bf16_t* __restrict__ A, const bf16_t* __restrict__ B,
             OutT* __restrict__ C0, OutT* __restrict__ C1,
             float* __restrict__ lsum,
             int M, int N, int Kps, int lda, int ldb, int ldc,
             long plane, int cshift, float alpha)
{
    __shared__ bf16_t As[128 * 64];   // 16KB
    __shared__ bf16_t Bs[256 * 64];   // 32KB

    const int tid  = threadIdx.x;
    const int wave = tid >> 6;
    const int lane = tid & 63;

    const int nbm = M >> 7, nbn = N >> 8;
    const int tiles = nbm * nbn;
    int bid = blockIdx.x;
    const int sid = bid / tiles;        // split-K id
    bid -= sid * tiles;
    const long kbase = (long)sid * Kps;
    OutT* __restrict__ C = sid ? C1 : C0;

    // XCD-chunked swizzle (bijective: tiles % 8 == 0 for our launches).
    const int cpx = tiles >> 3;
    bid = (bid & 7) * cpx + (bid >> 3);

    // grouped swizzle (GROUP_M row-tiles, col-major inside)
    const int per_group = GROUP_M * nbn;
    const int gid   = bid / per_group;
    const int rem   = bid - gid * per_group;
    const int first = gid * GROUP_M;
    const int gsz   = min(nbm - first, GROUP_M);
    const int bm    = first + rem % gsz;
    const int bn    = rem / gsz;
    const long row0 = (long)bm * 128;
    const long col0 = (long)bn * 256;

    const int wm = (wave >> 2) * 64;   // 2 row-waves
    const int wn = (wave & 3) * 64;    // 4 col-waves
    const int lr = lane & 15;          // fragment non-K index
    const int lq = lane >> 4;          // quad 0..3 -> k-chunk / row group

    // staging: rows rt=tid>>3 per 64-row block i; phys slot p=tid&7 holds
    // global chunk (p+r)&7 (rotation within the 128B row); r&7 == rt&7.
    const int rt = tid >> 3;
    const int sl = ((tid & 7) + rt) & 7;
    const bf16_t* pa = A + (row0 + rt) * (long)lda + kbase + sl * 8;
    const bf16_t* pb = B + (col0 + rt) * (long)ldb + kbase + sl * 8;

    // LDS read slot: chunk g at row r lives at p=(g-r)&7; r&7 == lr&7.
    const int p0  = (lq - lr) & 7;          // t=0 chunk = lq
    const int p1  = p0 ^ 4;                 // t=1 chunk = 4+lq
    const int oA0 = (wm + lr) * 64 + p0 * 8;
    const int oA1 = (wm + lr) * 64 + p1 * 8;
    const int oB0 = (wn + lr) * 64 + p0 * 8;
    const int oB1 = (wn + lr) * 64 + p1 * 8;

    f32x4 acc[4][4] = {};

    for (int k0 = 0; k0 < Kps; k0 += 64) {
        // Stage A (128x64: 2 chunks/thread) + B (256x64: 4 chunks/thread).
        #pragma unroll
        for (int i = 0; i < 2; ++i) {
            const bf16_t* ga = pa + k0 + (long)i * 64 * lda;
            __builtin_amdgcn_global_load_lds(
                (const __attribute__((address_space(1))) uint32_t*)ga,
                (__attribute__((address_space(3))) uint32_t*)(As + i * 4096 + tid * 8),
                16, 0, 0);
        }
        #pragma unroll
        for (int i = 0; i < 4; ++i) {
            const bf16_t* gb = pb + k0 + (long)i * 64 * ldb;
            __builtin_amdgcn_global_load_lds(
                (const __attribute__((address_space(1))) uint32_t*)gb,
                (__attribute__((address_space(3))) uint32_t*)(Bs + i * 4096 + tid * 8),
                16, 0, 0);
        }
        __syncthreads();

        #pragma unroll
        for (int t = 0; t < 2; ++t) {   // two K=32 MFMA steps per staged tile
            bf16x8 af[4], bfr[4];
            const int oA = t ? oA1 : oA0;
            const int oB = t ? oB1 : oB0;
            #pragma unroll
            for (int mi = 0; mi < 4; ++mi)
                af[mi] = *(const bf16x8*)(As + oA + mi * 1024);
            #pragma unroll
            for (int ni = 0; ni < 4; ++ni)
                bfr[ni] = *(const bf16x8*)(Bs + oB + ni * 1024);
            #pragma unroll
            for (int mi = 0; mi < 4; ++mi)
                #pragma unroll
                for (int ni = 0; ni < 4; ++ni)
                    acc[mi][ni] = __builtin_amdgcn_mfma_f32_16x16x32_bf16(
                        af[mi], bfr[ni], acc[mi][ni], 0, 0, 0);
        }
        __syncthreads();
    }

    // Epilogue: C/D layout col=lane&15, row=(lane>>4)*4+reg  [m89/m91]
    OutT* __restrict__ Cb = C + (col0 >> cshift) * plane;
    const int ccol0 = (int)(col0 & (((long)1 << cshift) - 1));

    if (MODE == 2) {
        #pragma unroll
        for (int mi = 0; mi < 4; ++mi)
            #pragma unroll
            for (int rg = 0; rg < 4; ++rg) {
                const long r = row0 + wm + mi * 16 + lq * 4 + rg;
                const float inv = 1.0f / lsum[r];
                #pragma unroll
                for (int ni = 0; ni < 4; ++ni) {
                    const int c = ccol0 + wn + ni * 16 + lr;
                    Cb[r * (long)ldc + c] = (OutT)(acc[mi][ni][rg] * inv);
                }
            }
    } else {
        #pragma unroll
        for (int mi = 0; mi < 4; ++mi)
            #pragma unroll
            for (int ni = 0; ni < 4; ++ni)
                #pragma unroll
                for (int rg = 0; rg < 4; ++rg) {
                    const long r = row0 + wm + mi * 16 + lq * 4 + rg;
                    const int  c = ccol0 + wn + ni * 16 + lr;
                    Cb[r * (long)ldc + c] = (OutT)(alpha * acc[mi][ni][rg]);
                }
    }
}

// ======================================================================
// gemm32: 128x128 tile, BK=32, 256 threads (4 waves 2x2), wave 64x64 via
// 4x4 grid of mfma_f32_16x16x32_bf16. DOUBLE-BUFFERED (R22): 2x16KB LDS,
// one-tile-ahead prefetch; per iter: vmcnt(0) [tile t's loads, issued one
// iter ago] -> s_barrier -> STG(t+1 -> buf^1) -> 8 frag ds_reads -> 16
// MFMA. One barrier/iter. (r>>1)-rotation swizzle: 0 bank conflicts.
// XCD chunking + GROUP_M. Used for the S-GEMM (MODE1).
// ======================================================================
template <typename OutT, int MODE>
__global__ __launch_bounds__(256, 3)
void gemm32(const bf16_t* __restrict__ A, const bf16_t* __restrict__ B,
            OutT* __restrict__ C0, OutT* __restrict__ C1,
            float* __restrict__ lsum,
            int M, int N, int Kps, int lda, int ldb, int ldc,
            long plane, int cshift, float alpha)
{
    __shared__ bf16_t As[2][128 * 32];   // 2 x 8KB
    __shared__ bf16_t Bs[2][128 * 32];   // 2 x 8KB

    const int tid  = threadIdx.x;
    const int wave = tid >> 6;
    const int lane = tid & 63;

    const int nbm = M >> 7, nbn = N >> 7;
    const int tiles = nbm * nbn;
    int bid = blockIdx.x;
    const int sid = bid / tiles;
    bid -= sid * tiles;
    const long kbase = (long)sid * Kps;
    OutT* __restrict__ C = sid ? C1 : C0;

    const int cpx = tiles >> 3;
    bid = (bid & 7) * cpx + (bid >> 3);

    const int per_group = GROUP_M * nbn;
    const int gid   = bid / per_group;
    const int rem   = bid - gid * per_group;
    const int first = gid * GROUP_M;
    const int gsz   = min(nbm - first, GROUP_M);
    const int bm    = first + rem % gsz;
    const int bn    = rem / gsz;
    const long row0 = (long)bm * 128;
    const long col0 = (long)bn * 128;

    const int wm = (wave >> 1) * 64;
    const int wn = (wave & 1) * 64;
    const int lr = lane & 15;
    const int lq = lane >> 4;

    // staging: chunk c=i*256+tid; row r=c>>2, phys slot p=c&3 holds global
    // chunk l=(p+(r>>1))&3; thread-constant l=((tid&3)+((tid>>3)&3))&3.
    const int rt = tid >> 2;
    const int sl = ((tid & 3) + ((tid >> 3) & 3)) & 3;
    const bf16_t* pa = A + (row0 + rt) * (long)lda + kbase + sl * 8;
    const bf16_t* pb = B + (col0 + rt) * (long)ldb + kbase + sl * 8;

    // read slot: p0=(lq-((r>>1)&3))&3; (r>>1)&3 == (lr>>1)&3.
    const int p0  = (lq - ((lr >> 1) & 3)) & 3;
    const int oA  = (wm + lr) * 32 + p0 * 8;
    const int oB  = (wn + lr) * 32 + p0 * 8;

    const int nt = Kps >> 5;   // 32-wide K-tiles

    f32x4 acc[4][4] = {};

#define STG32(kt, bsel)                                                         \
    {                                                                           \
        _Pragma("unroll")                                                       \
        for (int i = 0; i < 2; ++i) {                                           \
            const bf16_t* ga = pa + (long)(kt) * 32 + (long)i * 64 * lda;       \
            const bf16_t* gb = pb + (long)(kt) * 32 + (long)i * 64 * ldb;       \
            __builtin_amdgcn_global_load_lds(                                   \
                (const __attribute__((address_space(1))) uint32_t*)ga,          \
                (__attribute__((address_space(3))) uint32_t*)(As[bsel] + (long)(i * 256 + tid) * 8), \
                16, 0, 0);                                                      \
            __builtin_amdgcn_global_load_lds(                                   \
                (const __attribute__((address_space(1))) uint32_t*)gb,          \
                (__attribute__((address_space(3))) uint32_t*)(Bs[bsel] + (long)(i * 256 + tid) * 8), \
                16, 0, 0);                                                      \
        }                                                                       \
    }

    // Prologue: stage tile 0 into buf 0.
    STG32(0, 0);

    for (int t = 0; t < nt; ++t) {
        const int c = t & 1;
        const bf16_t* as = As[c];
        const bf16_t* bs = Bs[c];

        // Tile t's 4 loads (issued one iter ago) landed; CU-wide sync.
        // Barrier also guarantees every wave's ds_reads of buf c^1 (last
        // iter) retired -> safe to DMA tile t+1 over it below.
        asm volatile("s_waitcnt vmcnt(0)" ::: "memory");
        __builtin_amdgcn_s_barrier();
        asm volatile("" ::: "memory");   // no load hoisting above barrier

        if (t + 1 < nt) STG32(t + 1, c ^ 1);

        bf16x8 af[4], bfr[4];
        #pragma unroll
        for (int mi = 0; mi < 4; ++mi)
            af[mi] = *(const bf16x8*)(as + oA + mi * 512);
        #pragma unroll
        for (int ni = 0; ni < 4; ++ni)
            bfr[ni] = *(const bf16x8*)(bs + oB + ni * 512);
        #pragma unroll
        for (int mi = 0; mi < 4; ++mi)
            #pragma unroll
            for (int ni = 0; ni < 4; ++ni)
                acc[mi][ni] = __builtin_amdgcn_mfma_f32_16x16x32_bf16(
                    af[mi], bfr[ni], acc[mi][ni], 0, 0, 0);
    }
#undef STG32

    OutT* __restrict__ Cb = C + (col0 >> cshift) * plane;
    const int ccol0 = (int)(col0 & (((long)1 << cshift) - 1));

    if (MODE == 1) {
        #pragma unroll
        for (int mi = 0; mi < 4; ++mi)
            #pragma unroll
            for (int rg = 0; rg < 4; ++rg) {
                const long r = row0 + wm + mi * 16 + lq * 4 + rg;
                float part = 0.f;
                #pragma unroll
                for (int ni = 0; ni < 4; ++ni) {
                    const int c = ccol0 + wn + ni * 16 + lr;
                    const float e = exp2f(alpha * acc[mi][ni][rg]);
                    part += e;
                    Cb[r * (long)ldc + c] = (OutT)e;
                }
                part += __shfl_xor(part, 1);
                part += __shfl_xor(part, 2);
                part += __shfl_xor(part, 4);
                part += __shfl_xor(part, 8);
                if (lr == 0) atomicAdd(&lsum[r], part);
            }
    } else {
        #pragma unroll
        for (int mi = 0; mi < 4; ++mi)
            #pragma unroll
            for (int ni = 0; ni < 4; ++ni)
                #pragma unroll
                for (int rg = 0; rg < 4; ++rg) {
                    const long r = row0 + wm + mi * 16 + lq * 4 + rg;
                    const int  c = ccol0 + wn + ni * 16 + lr;
                    Cb[r * (long)ldc + c] = (OutT)(alpha * acc[mi][ni][rg]);
                }
    }
}

// ---------------- bf16 transpose (strided in), v -> v^T ----------------
__global__ __launch_bounds__(256)
void transpose_bf16(const bf16_t* __restrict__ in, bf16_t* __restrict__ out,
                    int R, int ldin, int ldout)
{
    __shared__ bf16_t tile[32][33];
    const int tx = threadIdx.x & 31;
    const int ty = threadIdx.x >> 5;   // 0..7
    const int c0 = blockIdx.x * 32;
    const int r0 = blockIdx.y * 32;
    #pragma unroll
    for (int j = 0; j < 32; j += 8)
        tile[ty + j][tx] = in[(long)(r0 + ty + j) * ldin + c0 + tx];
    __syncthreads();
    #pragma unroll
    for (int j = 0; j < 32; j += 8)
        out[(long)(c0 + ty + j) * ldout + r0 + tx] = tile[tx][ty + j];
}

extern "C" void kernel_launch(void* const* d_in, const int* in_sizes, int n_in,
                              void* d_out, int out_size, void* d_ws, size_t ws_size,
                              hipStream_t stream)
{
    const float* x  = (const float*)d_in[0];
    const float* Wq = (const float*)d_in[1];
    const float* Wk = (const float*)d_in[2];
    const float* Wv = (const float*)d_in[3];
    float* out = (float*)d_out;

    char* ws = (char*)d_ws;
    const long XN = (long)SEQ * DMODEL;     // 8,388,608
    const long WN = (long)DMODEL * DMODEL;  // 1,048,576
    const long SN = (long)SEQ * SEQ;        // 67,108,864

    bf16_t* xb   = (bf16_t*)ws;                              // 16MB
    bf16_t* wcat = (bf16_t*)(ws + XN * 2);                   // 6MB [3072,1024]
    bf16_t* qb   = (bf16_t*)(ws + XN * 2 + WN * 6);          // 16MB compact
    bf16_t* kb   = qb + XN;                                  // 16MB compact
    bf16_t* vb   = qb + 2 * XN;                              // 16MB compact
    bf16_t* Sb   = (bf16_t*)(ws + XN * 2 + WN * 6 + XN * 6); // 128MB
    float*  pvp  = (float*)(ws + XN * 2 + WN * 6 + XN * 6 + SN * 2); // 32MB
    float*  lsum = (float*)(ws + XN * 2 + WN * 6 + XN * 6 + SN * 2 + XN * 4); // 32KB
    bf16_t* vtb  = xb;  // v^T overlays x_bf16 (x dead after QKV GEMM)

    const size_t base_need = (size_t)(XN * 2 + WN * 6 + XN * 6 + SN * 2);
    const bool use_split = ws_size >= base_need + XN * 4 + SEQ * 4;
    if (!use_split) lsum = (float*)(ws + base_need);  // reuse pvp slot

    convert_f32_bf16<<<(int)(XN / 4 / 256), 256, 0, stream>>>(x,  xb, XN);
    convert_f32_bf16<<<(int)(WN / 4 / 256), 256, 0, stream>>>(Wq, wcat,          WN);
    convert_f32_bf16<<<(int)(WN / 4 / 256), 256, 0, stream>>>(Wk, wcat + WN,     WN);
    convert_f32_bf16<<<(int)(WN / 4 / 256), 256, 0, stream>>>(Wv, wcat + 2 * WN, WN);
    zero_f32<<<SEQ / 256, 256, 0, stream>>>(lsum, SEQ);

    dim3 blk256(256);
    dim3 blk512(512);
    // qkv = x @ Wcat^T, de-interleaved into compact q|k|v (plane=XN, cshift=10)
    gemm_hn<bf16_t, 0><<<(SEQ / 128) * (3 * DMODEL / 256), blk512, 0, stream>>>(
        xb, wcat, qb, qb, nullptr, SEQ, 3 * DMODEL, DMODEL,
        DMODEL, DMODEL, DMODEL, XN, 10, 1.0f);

    // v^T for the PV GEMM (writes over dead x_bf16)
    transpose_bf16<<<dim3(DMODEL / 32, SEQ / 32), blk256, 0, stream>>>(
        vb, vtb, SEQ, DMODEL, SEQ);

    // P' = exp2((q@k^T) * scale * log2e), bf16; row sums -> lsum (atomic)
    gemm32<bf16_t, 1><<<(SEQ / 128) * (SEQ / 128), blk256, 0, stream>>>(
        qb, kb, Sb, Sb, lsum, SEQ, SEQ, DMODEL,
        DMODEL, DMODEL, SEQ, 0, 30, 0.03125f * LOG2E);

    // out = (P' @ v) / l  (PV epilogue applies 1/lsum[row]). Split-K=2 if ws.
    if (use_split) {
        gemm_hn<float, 2><<<2 * (SEQ / 128) * (DMODEL / 256), blk512, 0, stream>>>(
            Sb, vtb, out, pvp, lsum, SEQ, DMODEL, SEQ / 2,
            SEQ, SEQ, DMODEL, 0, 30, 1.0f);
        add_f32<<<(int)(XN / 4 / 256), 256, 0, stream>>>(out, pvp, XN);
    } else {
        gemm_hn<float, 2><<<(SEQ / 128) * (DMODEL / 256), blk512, 0, stream>>>(
            Sb, vtb, out, out, lsum, SEQ, DMODEL, SEQ,
            SEQ, SEQ, DMODEL, 0, 30, 1.0f);
    }
}